// Round 1
// baseline (74.463 us; speedup 1.0000x reference)
//
#include <hip/hip_runtime.h>

// ProposalLayer: for each proposal (b,p), find nearest GT among the first
// num_person[b] GT slots, emit [xyz, proposal2gt, conf, bbox(2)] -> [B,P,7].
//
// B=256, P=1024, G=128. One thread per proposal; one block = 256 proposals
// of a single batch b, so gt_3d/gt_bbox for b are staged once in LDS and
// reused by all threads. Inner-loop LDS reads are wave-uniform (broadcast).

#define BB 256
#define PP 1024
#define GG 128

__global__ __launch_bounds__(256) void proposal_layer_kernel(
    const float* __restrict__ topk_index,   // [B,P,3]
    const float* __restrict__ topk_confs,   // [B,P]
    const float* __restrict__ bbox_preds,   // [B,P,2]
    const float* __restrict__ gt_3d,        // [B,G,3]
    const float* __restrict__ gt_bbox,      // [B,G,2]
    const int*   __restrict__ num_person,   // [B]
    float* __restrict__ out)                // [B,P,7]
{
    __shared__ float s_gt[GG * 3];   // 1536 B
    __shared__ float s_bb[GG * 2];   // 1024 B

    const int blocks_per_b = PP / 256;          // 4
    const int b     = blockIdx.x / blocks_per_b;
    const int ptile = blockIdx.x % blocks_per_b;
    const int p     = ptile * 256 + threadIdx.x;
    const int t     = threadIdx.x;

    // Stage GT data for this batch into LDS (coalesced).
    {
        const float* g3 = gt_3d + (size_t)b * (GG * 3);
        for (int i = t; i < GG * 3; i += 256) s_gt[i] = g3[i];
        const float* gb = gt_bbox + (size_t)b * (GG * 2);
        s_bb[t] = gb[t];                         // 256 floats exactly
    }
    const int np_b = num_person[b];              // scalar broadcast
    __syncthreads();

    const size_t bp = (size_t)b * PP + p;
    const float x = topk_index[bp * 3 + 0];
    const float y = topk_index[bp * 3 + 1];
    const float z = topk_index[bp * 3 + 2];

    // argmin over squared distance; strict < keeps first-occurrence semantics
    float best = 3.402823466e+38f;
    int   bidx = 0;
    for (int g = 0; g < np_b; ++g) {
        const float dx = x - s_gt[g * 3 + 0];
        const float dy = y - s_gt[g * 3 + 1];
        const float dz = z - s_gt[g * 3 + 2];
        const float d  = dx * dx + dy * dy + dz * dz;
        if (d < best) { best = d; bidx = g; }
    }

    // sqrt(best) > 500  <=>  best > 500^2 (both non-negative)
    const float p2g = (best > 500.0f * 500.0f) ? -1.0f : (float)bidx;

    // matched bbox gathered with min_gt unconditionally (matches reference)
    const float mb0 = s_bb[bidx * 2 + 0];
    const float mb1 = s_bb[bidx * 2 + 1];
    const float bp0 = bbox_preds[bp * 2 + 0];
    const float bp1 = bbox_preds[bp * 2 + 1];
    const bool cond = (p2g >= 0.0f) &&
                      ((bp0 < mb0 - 0.1f) || (bp1 < mb1 - 0.1f));
    const float o5 = cond ? mb0 : bp0;
    const float o6 = cond ? mb1 : bp1;

    const float conf = topk_confs[bp];

    float* o = out + bp * 7;
    o[0] = x;
    o[1] = y;
    o[2] = z;
    o[3] = p2g;
    o[4] = conf;
    o[5] = o5;
    o[6] = o6;
}

extern "C" void kernel_launch(void* const* d_in, const int* in_sizes, int n_in,
                              void* d_out, int out_size, void* d_ws, size_t ws_size,
                              hipStream_t stream) {
    const float* topk_index      = (const float*)d_in[0];
    const float* topk_confs      = (const float*)d_in[1];
    const float* match_bbox_preds= (const float*)d_in[2];
    const float* gt_3d           = (const float*)d_in[3];
    const float* gt_bbox         = (const float*)d_in[4];
    const int*   num_person      = (const int*)d_in[5];
    float* out = (float*)d_out;

    const int grid = BB * (PP / 256);   // 1024 blocks
    proposal_layer_kernel<<<grid, 256, 0, stream>>>(
        topk_index, topk_confs, match_bbox_preds, gt_3d, gt_bbox,
        num_person, out);
}